// Round 18
// baseline (128.261 us; speedup 1.0000x reference)
//
#include <hip/hip_runtime.h>

#define EPS 1e-12f

// Problem constants
#define NIMG   200      // 150 query + 50 support
#define NQIMG  150
#define BDIM   2
#define NQ     75
#define WAY    5
#define SHOT   5
#define DCH    64
#define H1     84
#define H2     42
#define H3     21
#define HW1    7056     // 84*84
#define HW2    1764     // 42*42
#define HW3    441      // 21*21
#define PH     86       // padded 84+2
#define PSZ    7396     // 86*86
#define SST    448      // padded support row stride
#define SLEN   4648     // strip buffer u16 elements (data 4644 + pad)

// prep kernel grid sections (pad is 4-wide per thread)
#define PAD_BLKS  4334      // ceil(200*3*7396/4 / 256)
#define W1_BLKS   8
#define W_BLKS    432       // 3*36864/256

typedef __attribute__((ext_vector_type(8))) short bf16x8;
typedef __attribute__((ext_vector_type(4))) float f32x4;
typedef __attribute__((ext_vector_type(4))) unsigned u32x4;

__device__ __forceinline__ unsigned short f2bf(float f) {
    unsigned u = __float_as_uint(f);
    u += 0x7fffu + ((u >> 16) & 1u);
    return (unsigned short)(u >> 16);
}
__device__ __forceinline__ float bf2f(unsigned short h) {
    return __uint_as_float(((unsigned)h) << 16);
}
// LDS pixel-line swizzle: 128B line per pixel, chunk ^= (pix>>1)&7
__device__ __forceinline__ int swz(int pix, int c) {
    return pix * 128 + ((c ^ ((pix >> 1) & 7)) << 4);
}

// ---------------- prep: pad input (4-wide) + pack all weights (scale folded) ----------------
__global__ __launch_bounds__(256) void prep(
    const float* __restrict__ qin, const float* __restrict__ sin_,
    const float* __restrict__ w1, const float* __restrict__ s1,
    const float* __restrict__ w2, const float* __restrict__ s2,
    const float* __restrict__ w3, const float* __restrict__ s3,
    const float* __restrict__ w4, const float* __restrict__ s4,
    unsigned short* __restrict__ pad, unsigned short* __restrict__ p1,
    unsigned short* __restrict__ p2, unsigned short* __restrict__ p3,
    unsigned short* __restrict__ p4)
{
    int blk = blockIdx.x;
    if (blk < PAD_BLKS) {
        int idx4 = blk * 256 + threadIdx.x;
        if (idx4 >= NIMG * 3 * PSZ / 4) return;
        int idx = idx4 * 4;
        int img = idx / (3 * PSZ);
        int rem = idx % (3 * PSZ);
        int ci = rem / PSZ, p = rem % PSZ;
        const float* src = (img < NQIMG) ? (qin + (size_t)img * 3 * HW1)
                                         : (sin_ + (size_t)(img - NQIMG) * 3 * HW1);
        unsigned short o[4];
        #pragma unroll
        for (int e = 0; e < 4; e++) {
            int pe = p + e;
            int iy = pe / PH, ix = pe % PH;
            float v = 0.f;
            if (iy >= 1 && iy <= H1 && ix >= 1 && ix <= H1)
                v = src[(size_t)ci * HW1 + (iy - 1) * H1 + (ix - 1)];
            o[e] = f2bf(v);
        }
        uint2 pk;
        pk.x = (unsigned)o[0] | ((unsigned)o[1] << 16);
        pk.y = (unsigned)o[2] | ((unsigned)o[3] << 16);
        *reinterpret_cast<uint2*>(pad + idx) = pk;
    } else if (blk < PAD_BLKS + W1_BLKS) {
        int idx = (blk - PAD_BLKS) * 256 + threadIdx.x;
        int j = idx & 7, lane = (idx >> 3) & 63, mt = idx >> 9;
        int co = (mt << 4) + (lane & 15);
        int k = ((lane >> 4) << 3) + j;
        float v = 0.f;
        if (k < 27) {
            int ci = k / 9, s = k % 9;
            v = w1[(co * 3 + ci) * 9 + s] * s1[co];
        }
        p1[idx] = f2bf(v);
    } else {
        int idx = (blk - PAD_BLKS - W1_BLKS) * 256 + threadIdx.x;
        int which = idx / 36864;
        int r = idx % 36864;
        int j = r & 7, lane = (r >> 3) & 63, mt = (r >> 9) & 3, t = (r >> 11) & 1, s = r >> 12;
        int co = (mt << 4) + (lane & 15);
        int ci = (t << 5) + ((lane >> 4) << 3) + j;
        const float* w = (which == 0) ? w2 : (which == 1) ? w3 : w4;
        const float* sc = (which == 0) ? s2 : (which == 1) ? s3 : s4;
        unsigned short* p = (which == 0) ? p2 : (which == 1) ? p3 : p4;
        p[r] = f2bf(w[(co * 64 + ci) * 9 + s] * sc[co]);
    }
}

// ---------------- conv1+conv2 fused ----------------
// Phase 1 : stage input strip [3][18][86] bf16 + shifted copy (stripB[i]=strip[i+1]).
// Phase 2 : conv1 im2col via paired ds_read_b32 (2 per tap), pool reg-max -> lds2.
// Phase 3 : conv2 with per-t 4x4 window register cache (16 b128 reads per t).
__global__ __launch_bounds__(256) void conv12_fused(
    const unsigned short* __restrict__ pad,   // [img][3][86][86] bf16
    const unsigned short* __restrict__ wp1, const float* __restrict__ bias1,
    const unsigned short* __restrict__ wp2, const float* __restrict__ bias2,
    unsigned short* __restrict__ out)         // [img][441][64] bf16
{
    int img = blockIdx.x / 7, tg = blockIdx.x % 7;
    int tid = threadIdx.x;
    __shared__ __attribute__((aligned(16))) unsigned short strips[2 * SLEN]; // 18,592 B
    __shared__ unsigned short lds2[352 * DCH];                               // 45,056 B

    unsigned* s_dw  = (unsigned*)strips;
    unsigned* sB_dw = (unsigned*)(strips + SLEN);

    // ---- phase 1: stage strip (dword copies; rows outside [-1,84] -> 0) ----
    const unsigned* srcd = (const unsigned*)pad;
    size_t ibase = (size_t)img * 3 * (PSZ / 2);
    #pragma unroll
    for (int it = 0; it < 10; it++) {
        int i = it * 256 + tid;
        if (i < 2322) {                       // 3 * 774 dwords
            int ci = i / 774, rem = i % 774;
            int sr = rem / 43, d = rem % 43;  // 43 dwords = 86 u16 per row
            int y = 12 * tg - 3 + sr;
            unsigned v = 0;
            if (y >= -1 && y <= 84)
                v = srcd[ibase + ci * 3698 + (y + 1) * 43 + d];
            s_dw[i] = v;
        }
    }
    __syncthreads();
    // ---- phase 1b: shifted copy stripB[i] = strip[i+1] ----
    #pragma unroll
    for (int it = 0; it < 10; it++) {
        int k = it * 256 + tid;
        if (k < 2322) {
            unsigned lo = s_dw[k];
            unsigned hi = (k + 1 < 2322) ? s_dw[k + 1] : 0u;
            sB_dw[k] = (lo >> 16) | (hi << 16);
        }
    }
    __syncthreads();

    int wv = tid >> 6, lane = tid & 63;
    int lc = lane & 15, kg = lane >> 4;

    // ---- phase 2: conv1 into lds2 ----
    {
        const bf16x8* w1v = (const bf16x8*)wp1;
        bf16x8 a0 = w1v[lane];
        bf16x8 a1 = w1v[64 + lane];
        bf16x8 a2 = w1v[128 + lane];
        bf16x8 a3 = w1v[192 + lane];

        int boff[8];
        #pragma unroll
        for (int j = 0; j < 8; j++) {
            int k = (kg << 3) + j;
            int kk = k < 27 ? k : 0;
            int ci = kk / 9, s = kk % 9;
            int off = ci * 1548 + (s / 3) * 86 + (s % 3);
            // paired dword source: even a -> strip[a], odd a -> stripB[a-1]
            boff[j] = (off & 1) ? 2 * (SLEN + off - 1) : 2 * off;
        }

        f32x4 bini[4];
        #pragma unroll
        for (int mt = 0; mt < 4; mt++) {
            float4 bq = *reinterpret_cast<const float4*>(bias1 + (mt << 4) + (kg << 2));
            bini[mt] = (f32x4){bq.x, bq.y, bq.z, bq.w};
        }

        #pragma unroll
        for (int rnd = 0; rnd < 6; rnd++) {
            int pl = rnd * 64 + wv * 16 + lc;     // pooled strip px 0..351
            bool instrip = pl < 352;
            int plc = instrip ? pl : 0;
            int rr = plc / 44, cc = plc % 44;
            int pr = 6 * tg - 1 + rr, pc = cc - 1;
            bool validpx = instrip && ((unsigned)pr < (unsigned)H2) && ((unsigned)pc < (unsigned)H2);
            int ccc = ((unsigned)pc < (unsigned)H2) ? cc : 1;
            int bb2 = ((2 * rr) * 86 + (2 * ccc - 2)) * 2;   // byte offset, 4-aligned

            unsigned v0[4], v1[4], v2[4], v3[4];
            #pragma unroll
            for (int jp = 0; jp < 4; jp++) {
                const char* p0 = (const char*)strips + bb2 + boff[2 * jp];
                const char* p1 = (const char*)strips + bb2 + boff[2 * jp + 1];
                unsigned dA1 = *(const unsigned*)(p0);
                unsigned dA2 = *(const unsigned*)(p0 + 172);
                unsigned dB1 = *(const unsigned*)(p1);
                unsigned dB2 = *(const unsigned*)(p1 + 172);
                v0[jp] = (dA1 & 0xffffu) | (dB1 << 16);
                v1[jp] = (dA1 >> 16) | (dB1 & 0xffff0000u);
                v2[jp] = (dA2 & 0xffffu) | (dB2 << 16);
                v3[jp] = (dA2 >> 16) | (dB2 & 0xffff0000u);
            }
            u32x4 t0 = (u32x4){v0[0], v0[1], v0[2], v0[3]};
            u32x4 t1 = (u32x4){v1[0], v1[1], v1[2], v1[3]};
            u32x4 t2 = (u32x4){v2[0], v2[1], v2[2], v2[3]};
            u32x4 t3 = (u32x4){v3[0], v3[1], v3[2], v3[3]};
            bf16x8 B0 = *(bf16x8*)&t0;
            bf16x8 B1 = *(bf16x8*)&t1;
            bf16x8 B2 = *(bf16x8*)&t2;
            bf16x8 B3 = *(bf16x8*)&t3;

            f32x4 acc[4][4];
            #pragma unroll
            for (int mt = 0; mt < 4; mt++)
                #pragma unroll
                for (int sub = 0; sub < 4; sub++)
                    acc[mt][sub] = bini[mt];
            acc[0][0] = __builtin_amdgcn_mfma_f32_16x16x32_bf16(a0, B0, acc[0][0], 0, 0, 0);
            acc[1][0] = __builtin_amdgcn_mfma_f32_16x16x32_bf16(a1, B0, acc[1][0], 0, 0, 0);
            acc[2][0] = __builtin_amdgcn_mfma_f32_16x16x32_bf16(a2, B0, acc[2][0], 0, 0, 0);
            acc[3][0] = __builtin_amdgcn_mfma_f32_16x16x32_bf16(a3, B0, acc[3][0], 0, 0, 0);
            acc[0][1] = __builtin_amdgcn_mfma_f32_16x16x32_bf16(a0, B1, acc[0][1], 0, 0, 0);
            acc[1][1] = __builtin_amdgcn_mfma_f32_16x16x32_bf16(a1, B1, acc[1][1], 0, 0, 0);
            acc[2][1] = __builtin_amdgcn_mfma_f32_16x16x32_bf16(a2, B1, acc[2][1], 0, 0, 0);
            acc[3][1] = __builtin_amdgcn_mfma_f32_16x16x32_bf16(a3, B1, acc[3][1], 0, 0, 0);
            acc[0][2] = __builtin_amdgcn_mfma_f32_16x16x32_bf16(a0, B2, acc[0][2], 0, 0, 0);
            acc[1][2] = __builtin_amdgcn_mfma_f32_16x16x32_bf16(a1, B2, acc[1][2], 0, 0, 0);
            acc[2][2] = __builtin_amdgcn_mfma_f32_16x16x32_bf16(a2, B2, acc[2][2], 0, 0, 0);
            acc[3][2] = __builtin_amdgcn_mfma_f32_16x16x32_bf16(a3, B2, acc[3][2], 0, 0, 0);
            acc[0][3] = __builtin_amdgcn_mfma_f32_16x16x32_bf16(a0, B3, acc[0][3], 0, 0, 0);
            acc[1][3] = __builtin_amdgcn_mfma_f32_16x16x32_bf16(a1, B3, acc[1][3], 0, 0, 0);
            acc[2][3] = __builtin_amdgcn_mfma_f32_16x16x32_bf16(a2, B3, acc[2][3], 0, 0, 0);
            acc[3][3] = __builtin_amdgcn_mfma_f32_16x16x32_bf16(a3, B3, acc[3][3], 0, 0, 0);

            if (instrip) {
                #pragma unroll
                for (int mt = 0; mt < 4; mt++) {
                    uint2 pk = make_uint2(0u, 0u);
                    if (validpx) {
                        unsigned short uo[4];
                        #pragma unroll
                        for (int r = 0; r < 4; r++) {
                            float m = fmaxf(fmaxf(acc[mt][0][r], acc[mt][1][r]),
                                            fmaxf(acc[mt][2][r], acc[mt][3][r]));
                            uo[r] = f2bf(fmaxf(m, 0.f));
                        }
                        pk.x = (unsigned)uo[0] | ((unsigned)uo[1] << 16);
                        pk.y = (unsigned)uo[2] | ((unsigned)uo[3] << 16);
                    }
                    int c = (mt << 1) + (kg >> 1);
                    *(uint2*)((char*)lds2 + swz(pl, c) + ((kg & 1) << 3)) = pk;
                }
            }
        }
    }
    __syncthreads();

    // ---- phase 3: conv2 from lds2 with 4x4 window register cache ----
    int p_local = wv * 16 + lc;
    bool valid = p_local < 63;
    int pl = valid ? p_local : 62;
    int pyl = pl / 21, pxl = pl % 21;

    f32x4 bini[4];
    #pragma unroll
    for (int mt = 0; mt < 4; mt++) {
        float4 bq = *reinterpret_cast<const float4*>(bias2 + (mt << 4) + (kg << 2));
        bini[mt] = (f32x4){bq.x, bq.y, bq.z, bq.w};
    }

    const bf16x8* wvv = (const bf16x8*)wp2;
    f32x4 acc[4][4];
    #pragma unroll
    for (int i = 0; i < 4; i++)
        #pragma unroll
        for (int j = 0; j < 4; j++)
            acc[i][j] = bini[i];

    #pragma unroll 1
    for (int t = 0; t < 2; t++) {
        int c = (t << 2) + kg;
        bf16x8 W[4][4];
        #pragma unroll
        for (int R = 0; R < 4; R++)
            #pragma unroll
            for (int C = 0; C < 4; C++) {
                int pix = (2 * pyl + R) * 44 + (2 * pxl + C);
                W[R][C] = *(const bf16x8*)((const char*)lds2 + swz(pix, c));
            }
        #pragma unroll
        for (int s = 0; s < 9; s++) {
            const int ky = s / 3, kx = s % 3;
            int fbase = ((s * 2 + t) * 4) << 6;
            bf16x8 a0 = wvv[fbase + lane];
            bf16x8 a1 = wvv[fbase + 64 + lane];
            bf16x8 a2 = wvv[fbase + 128 + lane];
            bf16x8 a3 = wvv[fbase + 192 + lane];
            #pragma unroll
            for (int sub = 0; sub < 4; sub++) {
                bf16x8 bb = W[ky + (sub >> 1)][kx + (sub & 1)];
                acc[0][sub] = __builtin_amdgcn_mfma_f32_16x16x32_bf16(a0, bb, acc[0][sub], 0, 0, 0);
                acc[1][sub] = __builtin_amdgcn_mfma_f32_16x16x32_bf16(a1, bb, acc[1][sub], 0, 0, 0);
                acc[2][sub] = __builtin_amdgcn_mfma_f32_16x16x32_bf16(a2, bb, acc[2][sub], 0, 0, 0);
                acc[3][sub] = __builtin_amdgcn_mfma_f32_16x16x32_bf16(a3, bb, acc[3][sub], 0, 0, 0);
            }
        }
    }

    if (!valid) return;
    int p = tg * 63 + p_local;
    #pragma unroll
    for (int mt = 0; mt < 4; mt++) {
        unsigned short uo[4];
        #pragma unroll
        for (int r = 0; r < 4; r++) {
            float m = fmaxf(fmaxf(acc[mt][0][r], acc[mt][1][r]),
                            fmaxf(acc[mt][2][r], acc[mt][3][r]));
            uo[r] = f2bf(fmaxf(m, 0.f));
        }
        uint2 pk;
        pk.x = (unsigned)uo[0] | ((unsigned)uo[1] << 16);
        pk.y = (unsigned)uo[2] | ((unsigned)uo[3] << 16);
        *reinterpret_cast<uint2*>(out + ((size_t)img * HW3 + p) * DCH + (mt << 4) + (kg << 2)) = pk;
    }
}

// ---------------- conv3+conv4 fused (+q_norm for query imgs), 256 threads ----------------
__global__ __launch_bounds__(256) void conv34_fused(
    const unsigned short* __restrict__ act,   // [img][441][64] (conv2 out)
    const unsigned short* __restrict__ wp3, const unsigned short* __restrict__ wp4,
    const float* __restrict__ b3, const float* __restrict__ b4,
    unsigned short* __restrict__ a4out,       // support: [img][441][64]
    unsigned short* __restrict__ qlout)       // query:   [img][441][64] normalized
{
    int img = blockIdx.x;
    int tid = threadIdx.x;
    __shared__ unsigned short lds[529 * DCH];   // 67,712 B

    const unsigned short* ab = act + (size_t)img * HW3 * DCH;
    #pragma unroll
    for (int it = 0; it < 17; it++) {
        int idx = it * 256 + tid;
        if (idx < 529 * 8) {
            int pix = idx >> 3, c = idx & 7;
            int r = pix / 23, xx = pix % 23;
            int y = r - 1, x = xx - 1;
            bf16x8 v = (bf16x8)(short)0;
            if ((unsigned)y < (unsigned)H3 && (unsigned)x < (unsigned)H3)
                v = *(const bf16x8*)(ab + ((size_t)(y * H3 + x)) * DCH + (c << 3));
            *(bf16x8*)((char*)lds + swz(pix, c)) = v;
        }
    }
    __syncthreads();

    int wv = tid >> 6, lane = tid & 63;
    int lc = lane & 15, kg = lane >> 4;
    int pixBase[7];
    bool pv[7];
    #pragma unroll
    for (int i = 0; i < 7; i++) {
        int p = (wv * 7 + i) * 16 + lc;
        pv[i] = p < HW3;
        int pc = pv[i] ? p : HW3 - 1;
        pixBase[i] = (pc / 21) * 23 + (pc % 21);
    }

    // ---- conv3 ----
    f32x4 bini[4];
    #pragma unroll
    for (int mt = 0; mt < 4; mt++) {
        float4 bq = *reinterpret_cast<const float4*>(b3 + (mt << 4) + (kg << 2));
        bini[mt] = (f32x4){bq.x, bq.y, bq.z, bq.w};
    }

    f32x4 acc[7][4];
    #pragma unroll
    for (int i = 0; i < 7; i++)
        #pragma unroll
        for (int m = 0; m < 4; m++)
            acc[i][m] = bini[m];

    const bf16x8* wv3 = (const bf16x8*)wp3;
    for (int s = 0; s < 9; s++) {
        int offs = (s / 3) * 23 + (s % 3);
        #pragma unroll
        for (int t = 0; t < 2; t++) {
            int fbase = ((s * 2 + t) * 4) << 6;
            bf16x8 a0 = wv3[fbase + lane];
            bf16x8 a1 = wv3[fbase + 64 + lane];
            bf16x8 a2 = wv3[fbase + 128 + lane];
            bf16x8 a3 = wv3[fbase + 192 + lane];
            int c = (t << 2) + kg;
            #pragma unroll
            for (int i = 0; i < 7; i++) {
                int pix = pixBase[i] + offs;
                bf16x8 bb = *(const bf16x8*)((const char*)lds + swz(pix, c));
                acc[i][0] = __builtin_amdgcn_mfma_f32_16x16x32_bf16(a0, bb, acc[i][0], 0, 0, 0);
                acc[i][1] = __builtin_amdgcn_mfma_f32_16x16x32_bf16(a1, bb, acc[i][1], 0, 0, 0);
                acc[i][2] = __builtin_amdgcn_mfma_f32_16x16x32_bf16(a2, bb, acc[i][2], 0, 0, 0);
                acc[i][3] = __builtin_amdgcn_mfma_f32_16x16x32_bf16(a3, bb, acc[i][3], 0, 0, 0);
            }
        }
    }

    __syncthreads();   // all conv3 LDS reads done before overwrite

    #pragma unroll
    for (int i = 0; i < 7; i++) {
        if (!pv[i]) continue;
        int pix = pixBase[i] + 24;   // interior: (py+1)*23 + (px+1)
        #pragma unroll
        for (int mt = 0; mt < 4; mt++) {
            unsigned short uo[4];
            #pragma unroll
            for (int r = 0; r < 4; r++)
                uo[r] = f2bf(fmaxf(acc[i][mt][r], 0.f));
            uint2 pk;
            pk.x = (unsigned)uo[0] | ((unsigned)uo[1] << 16);
            pk.y = (unsigned)uo[2] | ((unsigned)uo[3] << 16);
            int c = (mt << 1) + (kg >> 1);
            *(uint2*)((char*)lds + swz(pix, c) + ((kg & 1) << 3)) = pk;
        }
    }
    // zero the 88 halo lines (704 16B chunks)
    #pragma unroll
    for (int it = 0; it < 3; it++) {
        int idx = it * 256 + tid;
        if (idx < 704) {
            int j = idx >> 3, c = idx & 7;
            int pix;
            if (j < 23)      pix = j;
            else if (j < 46) pix = 506 + (j - 23);
            else { int k = j - 46; pix = (1 + (k >> 1)) * 23 + (k & 1) * 22; }
            *(bf16x8*)((char*)lds + swz(pix, c)) = (bf16x8)(short)0;
        }
    }
    __syncthreads();

    // ---- conv4 ----
    #pragma unroll
    for (int mt = 0; mt < 4; mt++) {
        float4 bq = *reinterpret_cast<const float4*>(b4 + (mt << 4) + (kg << 2));
        bini[mt] = (f32x4){bq.x, bq.y, bq.z, bq.w};
    }
    #pragma unroll
    for (int i = 0; i < 7; i++)
        #pragma unroll
        for (int m = 0; m < 4; m++)
            acc[i][m] = bini[m];

    const bf16x8* wv4 = (const bf16x8*)wp4;
    for (int s = 0; s < 9; s++) {
        int offs = (s / 3) * 23 + (s % 3);
        #pragma unroll
        for (int t = 0; t < 2; t++) {
            int fbase = ((s * 2 + t) * 4) << 6;
            bf16x8 a0 = wv4[fbase + lane];
            bf16x8 a1 = wv4[fbase + 64 + lane];
            bf16x8 a2 = wv4[fbase + 128 + lane];
            bf16x8 a3 = wv4[fbase + 192 + lane];
            int c = (t << 2) + kg;
            #pragma unroll
            for (int i = 0; i < 7; i++) {
                int pix = pixBase[i] + offs;
                bf16x8 bb = *(const bf16x8*)((const char*)lds + swz(pix, c));
                acc[i][0] = __builtin_amdgcn_mfma_f32_16x16x32_bf16(a0, bb, acc[i][0], 0, 0, 0);
                acc[i][1] = __builtin_amdgcn_mfma_f32_16x16x32_bf16(a1, bb, acc[i][1], 0, 0, 0);
                acc[i][2] = __builtin_amdgcn_mfma_f32_16x16x32_bf16(a2, bb, acc[i][2], 0, 0, 0);
                acc[i][3] = __builtin_amdgcn_mfma_f32_16x16x32_bf16(a3, bb, acc[i][3], 0, 0, 0);
            }
        }
    }

    // ---- epilogue ----
    if (img < NQIMG) {
        #pragma unroll
        for (int i = 0; i < 7; i++) {
            float v[4][4];
            float ssq = 0.f;
            #pragma unroll
            for (int mt = 0; mt < 4; mt++)
                #pragma unroll
                for (int r = 0; r < 4; r++) {
                    float x = fmaxf(acc[i][mt][r], 0.f);
                    v[mt][r] = x;
                    ssq = fmaf(x, x, ssq);
                }
            ssq += __shfl_xor(ssq, 16, 64);
            ssq += __shfl_xor(ssq, 32, 64);
            float inv = 1.f / fmaxf(sqrtf(ssq), EPS);
            if (!pv[i]) continue;
            int p = (wv * 7 + i) * 16 + lc;
            #pragma unroll
            for (int mt = 0; mt < 4; mt++) {
                unsigned short uo[4];
                #pragma unroll
                for (int r = 0; r < 4; r++)
                    uo[r] = f2bf(v[mt][r] * inv);
                uint2 pk;
                pk.x = (unsigned)uo[0] | ((unsigned)uo[1] << 16);
                pk.y = (unsigned)uo[2] | ((unsigned)uo[3] << 16);
                *reinterpret_cast<uint2*>(qlout + ((size_t)img * HW3 + p) * DCH + (mt << 4) + (kg << 2)) = pk;
            }
        }
    } else {
        #pragma unroll
        for (int mt = 0; mt < 4; mt++) {
            #pragma unroll
            for (int i = 0; i < 7; i++) {
                if (!pv[i]) continue;
                int p = (wv * 7 + i) * 16 + lc;
                unsigned short uo[4];
                #pragma unroll
                for (int r = 0; r < 4; r++)
                    uo[r] = f2bf(fmaxf(acc[i][mt][r], 0.f));
                uint2 pk;
                pk.x = (unsigned)uo[0] | ((unsigned)uo[1] << 16);
                pk.y = (unsigned)uo[2] | ((unsigned)uo[3] << 16);
                *reinterpret_cast<uint2*>(a4out + ((size_t)img * HW3 + p) * DCH + (mt << 4) + (kg << 2)) = pk;
            }
        }
    }
}

// ---------------- support: mean over shots + L2-norm -> [bc][448][64] bf16, zero tail ----------------
__global__ __launch_bounds__(256) void s_mean_norm(
    const unsigned short* __restrict__ feat, unsigned short* __restrict__ s_local)
{
    int idx = blockIdx.x * 256 + threadIdx.x;
    if (idx >= BDIM * WAY * SST) return;
    int hw = idx % SST;
    int bc = idx / SST;
    bf16x8* o = (bf16x8*)(s_local + (size_t)idx * DCH);
    if (hw >= HW3) {
        #pragma unroll
        for (int g = 0; g < 8; g++) o[g] = (bf16x8)(short)0;
        return;
    }
    int img0 = NQIMG + bc * SHOT;
    float v[DCH];
    #pragma unroll
    for (int d = 0; d < DCH; d++) v[d] = 0.f;
    for (int sh = 0; sh < SHOT; sh++) {
        const bf16x8* f = (const bf16x8*)(feat + ((size_t)(img0 + sh) * HW3 + hw) * DCH);
        #pragma unroll
        for (int g = 0; g < 8; g++) {
            bf16x8 x = f[g];
            #pragma unroll
            for (int j = 0; j < 8; j++)
                v[g * 8 + j] += bf2f((unsigned short)x[j]);
        }
    }
    float ss = 0.f;
    #pragma unroll
    for (int d = 0; d < DCH; d++) {
        v[d] *= (1.f / SHOT);
        ss = fmaf(v[d], v[d], ss);
    }
    float inv = 1.f / fmaxf(sqrtf(ss), EPS);
    #pragma unroll
    for (int g = 0; g < 8; g++) {
        bf16x8 pk;
        #pragma unroll
        for (int j = 0; j < 8; j++) pk[j] = (short)f2bf(v[g * 8 + j] * inv);
        o[g] = pk;
    }
}

// ---------------- similarity via MFMA: s staged in swizzled LDS, 4 n-tiles/group ----------------
__global__ __launch_bounds__(256) void sim_mfma(
    const unsigned short* __restrict__ qloc,  // [150][441][64] bf16
    const unsigned short* __restrict__ sloc,  // [10][448][64] bf16 (tail zeroed)
    float* __restrict__ out)
{
    int blk = blockIdx.x;
    int imgq = blk / WAY, way = blk % WAY;
    int b = imgq / NQ;
    const unsigned short* qp = qloc + (size_t)imgq * HW3 * DCH;
    const unsigned short* sp = sloc + (size_t)(b * WAY + way) * SST * DCH;

    __shared__ unsigned short slds[SST * DCH];   // 57,344 B
    int tid = threadIdx.x;
    #pragma unroll
    for (int it = 0; it < 14; it++) {
        int idx = it * 256 + tid;              // 0..3583
        int pix = idx >> 3, c = idx & 7;
        bf16x8 v = *(const bf16x8*)(sp + ((size_t)pix << 6) + (c << 3));
        *(bf16x8*)((char*)slds + swz(pix, c)) = v;
    }
    __syncthreads();

    int wv = tid >> 6, lane = tid & 63;
    int lc = lane & 15, kg = lane >> 4;
    int mt0 = wv * 7;

    bf16x8 qa0[7], qa1[7];
    #pragma unroll
    for (int i = 0; i < 7; i++) {
        const unsigned short* qrow = qp + (size_t)((mt0 + i) * 16 + lc) * DCH + (kg << 3);
        qa0[i] = *(const bf16x8*)(qrow);
        qa1[i] = *(const bf16x8*)(qrow + 32);
    }
    f32x4 rmax[7];
    #pragma unroll
    for (int i = 0; i < 7; i++)
        rmax[i] = (f32x4){-1e30f, -1e30f, -1e30f, -1e30f};

    const f32x4 z4 = (f32x4){0.f, 0.f, 0.f, 0.f};

    #pragma unroll
    for (int g = 0; g < 6; g++) {
        bf16x8 s0[4], s1[4];
        #pragma unroll
        for (int u = 0; u < 4; u++) {
            int pix = (4 * g + u) * 16 + lc;
            s0[u] = *(const bf16x8*)((const char*)slds + swz(pix, kg));
            s1[u] = *(const bf16x8*)((const char*)slds + swz(pix, 4 + kg));
        }
        #pragma unroll
        for (int i = 0; i < 7; i++) {
            f32x4 a[4];
            #pragma unroll
            for (int u = 0; u < 4; u++) {
                a[u] = __builtin_amdgcn_mfma_f32_16x16x32_bf16(qa0[i], s0[u], z4, 0, 0, 0);
                a[u] = __builtin_amdgcn_mfma_f32_16x16x32_bf16(qa1[i], s1[u], a[u], 0, 0, 0);
            }
            #pragma unroll
            for (int r = 0; r < 4; r++) {
                float t = fmaxf(fmaxf(rmax[i][r], a[0][r]), a[1][r]);
                rmax[i][r] = fmaxf(fmaxf(t, a[2][r]), a[3][r]);
            }
        }
    }
    {   // tail tiles 24..27 (tile 27 cols 432..447: mask >= 441)
        bf16x8 s0[4], s1[4];
        #pragma unroll
        for (int u = 0; u < 4; u++) {
            int pix = (24 + u) * 16 + lc;
            s0[u] = *(const bf16x8*)((const char*)slds + swz(pix, kg));
            s1[u] = *(const bf16x8*)((const char*)slds + swz(pix, 4 + kg));
        }
        bool nval = (432 + lc) < HW3;
        #pragma unroll
        for (int i = 0; i < 7; i++) {
            f32x4 a[4];
            #pragma unroll
            for (int u = 0; u < 4; u++) {
                a[u] = __builtin_amdgcn_mfma_f32_16x16x32_bf16(qa0[i], s0[u], z4, 0, 0, 0);
                a[u] = __builtin_amdgcn_mfma_f32_16x16x32_bf16(qa1[i], s1[u], a[u], 0, 0, 0);
            }
            #pragma unroll
            for (int r = 0; r < 4; r++) {
                float t = fmaxf(fmaxf(rmax[i][r], a[0][r]), a[1][r]);
                rmax[i][r] = fmaxf(fmaxf(t, a[2][r]), nval ? a[3][r] : -1e30f);
            }
        }
    }

    float msum = 0.f;
    #pragma unroll
    for (int i = 0; i < 7; i++) {
        #pragma unroll
        for (int r = 0; r < 4; r++) {
            float v = rmax[i][r];
            v = fmaxf(v, __shfl_xor(v, 1, 64));
            v = fmaxf(v, __shfl_xor(v, 2, 64));
            v = fmaxf(v, __shfl_xor(v, 4, 64));
            v = fmaxf(v, __shfl_xor(v, 8, 64));
            int m = (mt0 + i) * 16 + (kg << 2) + r;
            if (lc == 0 && m < HW3) msum += v;
        }
    }
    #pragma unroll
    for (int off = 32; off > 0; off >>= 1)
        msum += __shfl_xor(msum, off, 64);
    __shared__ float red[4];
    if (lane == 0) red[wv] = msum;
    __syncthreads();
    if (tid == 0)
        out[(size_t)imgq * WAY + way] = (red[0] + red[1] + red[2] + red[3]) * (1.f / HW3);
}

extern "C" void kernel_launch(void* const* d_in, const int* in_sizes, int n_in,
                              void* d_out, int out_size, void* d_ws, size_t ws_size,
                              hipStream_t stream) {
    const float* query   = (const float*)d_in[0];
    const float* support = (const float*)d_in[1];
    const float* w1 = (const float*)d_in[2];
    const float* w2 = (const float*)d_in[3];
    const float* w3 = (const float*)d_in[4];
    const float* w4 = (const float*)d_in[5];
    const float* s1 = (const float*)d_in[6];
    const float* b1 = (const float*)d_in[7];
    const float* s2 = (const float*)d_in[8];
    const float* b2 = (const float*)d_in[9];
    const float* s3 = (const float*)d_in[10];
    const float* b3 = (const float*)d_in[11];
    const float* s4 = (const float*)d_in[12];
    const float* b4 = (const float*)d_in[13];
    float* out = (float*)d_out;

    char* ws = (char*)d_ws;
    unsigned short* A2  = (unsigned short*)(ws);              // 200*441*64 bf16 = 11,289,600 B
    unsigned short* A4  = (unsigned short*)(ws + 11289600);   // support feat (only >=150 written)
    unsigned short* QL  = (unsigned short*)(ws + 22579200);   // 150*441*64 bf16 = 8,467,200 B
    unsigned short* SL  = (unsigned short*)(ws + 31046400);   // 10*448*64 bf16 = 573,440 B
    unsigned short* WP2 = (unsigned short*)(ws + 31619840);   // 36864 bf16 = 73,728 B
    unsigned short* WP3 = (unsigned short*)(ws + 31693568);
    unsigned short* WP4 = (unsigned short*)(ws + 31767296);
    unsigned short* WP1 = (unsigned short*)(ws + 31841024);   // 2048 bf16 = 4,096 B
    unsigned short* PAD = (unsigned short*)(ws + 31845120);   // 200*3*7396 bf16 = 8,875,200 B

    prep<<<PAD_BLKS + W1_BLKS + W_BLKS, 256, 0, stream>>>(
        query, support, w1, s1, w2, s2, w3, s3, w4, s4, PAD, WP1, WP2, WP3, WP4);

    conv12_fused<<<NIMG * 7, 256, 0, stream>>>(PAD, WP1, b1, WP2, b2, A2);
    conv34_fused<<<NIMG, 256, 0, stream>>>(A2, WP3, WP4, b3, b4, A4, QL);

    s_mean_norm<<<(BDIM * WAY * SST + 255) / 256, 256, 0, stream>>>(A4, SL);

    sim_mfma<<<NQIMG * WAY, 256, 0, stream>>>(QL, SL, out);
}

// Round 19
// 125.951 us; speedup vs baseline: 1.0183x; 1.0183x over previous
//
#include <hip/hip_runtime.h>

#define EPS 1e-12f

// Problem constants
#define NIMG   200      // 150 query + 50 support
#define NQIMG  150
#define BDIM   2
#define NQ     75
#define WAY    5
#define SHOT   5
#define DCH    64
#define H1     84
#define H2     42
#define H3     21
#define HW1    7056     // 84*84
#define HW2    1764     // 42*42
#define HW3    441      // 21*21
#define PH     86       // padded 84+2
#define PSZ    7396     // 86*86
#define SST    448      // padded support row stride

// prep kernel grid sections (pad is 4-wide per thread)
#define PAD_BLKS  4334      // ceil(200*3*7396/4 / 256)
#define W1_BLKS   8
#define W_BLKS    432       // 3*36864/256

typedef __attribute__((ext_vector_type(8))) short bf16x8;
typedef __attribute__((ext_vector_type(4))) float f32x4;

__device__ __forceinline__ unsigned short f2bf(float f) {
    unsigned u = __float_as_uint(f);
    u += 0x7fffu + ((u >> 16) & 1u);
    return (unsigned short)(u >> 16);
}
__device__ __forceinline__ float bf2f(unsigned short h) {
    return __uint_as_float(((unsigned)h) << 16);
}
// LDS pixel-line swizzle: 128B line per pixel, chunk ^= (pix>>1)&7
__device__ __forceinline__ int swz(int pix, int c) {
    return pix * 128 + ((c ^ ((pix >> 1) & 7)) << 4);
}

// ---------------- prep: pad input (4-wide) + pack all weights (scale folded) ----------------
__global__ __launch_bounds__(256) void prep(
    const float* __restrict__ qin, const float* __restrict__ sin_,
    const float* __restrict__ w1, const float* __restrict__ s1,
    const float* __restrict__ w2, const float* __restrict__ s2,
    const float* __restrict__ w3, const float* __restrict__ s3,
    const float* __restrict__ w4, const float* __restrict__ s4,
    unsigned short* __restrict__ pad, unsigned short* __restrict__ p1,
    unsigned short* __restrict__ p2, unsigned short* __restrict__ p3,
    unsigned short* __restrict__ p4)
{
    int blk = blockIdx.x;
    if (blk < PAD_BLKS) {
        int idx4 = blk * 256 + threadIdx.x;
        if (idx4 >= NIMG * 3 * PSZ / 4) return;
        int idx = idx4 * 4;
        int img = idx / (3 * PSZ);
        int rem = idx % (3 * PSZ);
        int ci = rem / PSZ, p = rem % PSZ;
        const float* src = (img < NQIMG) ? (qin + (size_t)img * 3 * HW1)
                                         : (sin_ + (size_t)(img - NQIMG) * 3 * HW1);
        unsigned short o[4];
        #pragma unroll
        for (int e = 0; e < 4; e++) {
            int pe = p + e;
            int iy = pe / PH, ix = pe % PH;
            float v = 0.f;
            if (iy >= 1 && iy <= H1 && ix >= 1 && ix <= H1)
                v = src[(size_t)ci * HW1 + (iy - 1) * H1 + (ix - 1)];
            o[e] = f2bf(v);
        }
        uint2 pk;
        pk.x = (unsigned)o[0] | ((unsigned)o[1] << 16);
        pk.y = (unsigned)o[2] | ((unsigned)o[3] << 16);
        *reinterpret_cast<uint2*>(pad + idx) = pk;
    } else if (blk < PAD_BLKS + W1_BLKS) {
        int idx = (blk - PAD_BLKS) * 256 + threadIdx.x;
        int j = idx & 7, lane = (idx >> 3) & 63, mt = idx >> 9;
        int co = (mt << 4) + (lane & 15);
        int k = ((lane >> 4) << 3) + j;
        float v = 0.f;
        if (k < 27) {
            int ci = k / 9, s = k % 9;
            v = w1[(co * 3 + ci) * 9 + s] * s1[co];
        }
        p1[idx] = f2bf(v);
    } else {
        int idx = (blk - PAD_BLKS - W1_BLKS) * 256 + threadIdx.x;
        int which = idx / 36864;
        int r = idx % 36864;
        int j = r & 7, lane = (r >> 3) & 63, mt = (r >> 9) & 3, t = (r >> 11) & 1, s = r >> 12;
        int co = (mt << 4) + (lane & 15);
        int ci = (t << 5) + ((lane >> 4) << 3) + j;
        const float* w = (which == 0) ? w2 : (which == 1) ? w3 : w4;
        const float* sc = (which == 0) ? s2 : (which == 1) ? s3 : s4;
        unsigned short* p = (which == 0) ? p2 : (which == 1) ? p3 : p4;
        p[r] = f2bf(w[(co * 64 + ci) * 9 + s] * sc[co]);
    }
}

// ---------------- conv1: LDS strip stage + ds-gather im2col, reg-max pool ----------------
__global__ __launch_bounds__(256) void conv1_mfma(
    const unsigned short* __restrict__ pad,   // [img][3][86][86] bf16
    const unsigned short* __restrict__ wp1,
    const float* __restrict__ bias,
    unsigned short* __restrict__ out)         // [img][1764][64] bf16
{
    int img = blockIdx.x / 7, seg = blockIdx.x % 7;
    int tid = threadIdx.x;
    __shared__ unsigned short strip[3 * 14 * 86];   // 7224 B

    const unsigned* srcd = (const unsigned*)pad;
    size_t ibase = (size_t)img * 3 * (PSZ / 2);
    #pragma unroll
    for (int it = 0; it < 8; it++) {
        int i = it * 256 + tid;
        if (i < 1806) {
            int ci = i / 602, r = i % 602;
            ((unsigned*)strip)[i] = srcd[ibase + ci * (PSZ / 2) + 516 * seg + r];
        }
    }
    __syncthreads();

    int wv = tid >> 6, lane = tid & 63;
    int lc = lane & 15, kg = lane >> 4;

    const bf16x8* wvv = (const bf16x8*)wp1;
    bf16x8 a0 = wvv[lane];
    bf16x8 a1 = wvv[64 + lane];
    bf16x8 a2 = wvv[128 + lane];
    bf16x8 a3 = wvv[192 + lane];

    int off[8];
    #pragma unroll
    for (int j = 0; j < 8; j++) {
        int k = (kg << 3) + j;
        int kk = k < 27 ? k : 0;
        int ci = kk / 9, s = kk % 9;
        off[j] = ci * 1204 + (s / 3) * 86 + (s % 3);
    }

    f32x4 bini[4];
    #pragma unroll
    for (int mt = 0; mt < 4; mt++) {
        float4 bq = *reinterpret_cast<const float4*>(bias + (mt << 4) + (kg << 2));
        bini[mt] = (f32x4){bq.x, bq.y, bq.z, bq.w};
    }

    #pragma unroll
    for (int it = 0; it < 4; it++) {
        int pl = it * 64 + wv * 16 + lc;
        bool valid = pl < 252;
        int plc = valid ? pl : 251;
        int pyl = plc / 42, pxl = plc % 42;
        int base = pyl * 172 + 2 * pxl;

        bf16x8 b[4];
        #pragma unroll
        for (int j = 0; j < 8; j++) {
            int a = base + off[j];
            b[0][j] = (short)strip[a];
            b[1][j] = (short)strip[a + 1];
            b[2][j] = (short)strip[a + 86];
            b[3][j] = (short)strip[a + 87];
        }

        f32x4 acc[4][4];
        #pragma unroll
        for (int mt = 0; mt < 4; mt++)
            #pragma unroll
            for (int sub = 0; sub < 4; sub++)
                acc[mt][sub] = bini[mt];
        #pragma unroll
        for (int sub = 0; sub < 4; sub++) {
            acc[0][sub] = __builtin_amdgcn_mfma_f32_16x16x32_bf16(a0, b[sub], acc[0][sub], 0, 0, 0);
            acc[1][sub] = __builtin_amdgcn_mfma_f32_16x16x32_bf16(a1, b[sub], acc[1][sub], 0, 0, 0);
            acc[2][sub] = __builtin_amdgcn_mfma_f32_16x16x32_bf16(a2, b[sub], acc[2][sub], 0, 0, 0);
            acc[3][sub] = __builtin_amdgcn_mfma_f32_16x16x32_bf16(a3, b[sub], acc[3][sub], 0, 0, 0);
        }

        if (valid) {
            int p = seg * 252 + pl;
            #pragma unroll
            for (int mt = 0; mt < 4; mt++) {
                unsigned short uo[4];
                #pragma unroll
                for (int r = 0; r < 4; r++) {
                    float m = fmaxf(fmaxf(acc[mt][0][r], acc[mt][1][r]),
                                    fmaxf(acc[mt][2][r], acc[mt][3][r]));
                    uo[r] = f2bf(fmaxf(m, 0.f));
                }
                uint2 pk;
                pk.x = (unsigned)uo[0] | ((unsigned)uo[1] << 16);
                pk.y = (unsigned)uo[2] | ((unsigned)uo[3] << 16);
                *reinterpret_cast<uint2*>(out + ((size_t)img * HW2 + p) * DCH + (mt << 4) + (kg << 2)) = pk;
            }
        }
    }
}

// ---------------- conv2: 64->64 MFMA + LDS strip staging, bias-init, pool, ReLU ----------------
__global__ __launch_bounds__(256) void conv2_mfma_pool(
    const unsigned short* __restrict__ act,   // [img][1764][64]
    const unsigned short* __restrict__ wp,
    const float* __restrict__ bias,
    unsigned short* __restrict__ out)         // [img][441][64]
{
    int img = blockIdx.x / 7, tg = blockIdx.x % 7;
    int tid = threadIdx.x;
    __shared__ unsigned short lds[8 * 44 * DCH];   // 45,056 B

    const unsigned short* ab = act + (size_t)img * HW2 * DCH;
    int ybase = 6 * tg - 1;
    #pragma unroll
    for (int it = 0; it < 11; it++) {
        int idx = it * 256 + tid;
        int pix = idx >> 3, c = idx & 7;
        int r = pix / 44, xx = pix % 44;
        int y = ybase + r, x = xx - 1;
        bf16x8 v = (bf16x8)(short)0;
        if ((unsigned)y < (unsigned)H2 && (unsigned)x < (unsigned)H2)
            v = *(const bf16x8*)(ab + ((size_t)(y * H2 + x)) * DCH + (c << 3));
        *(bf16x8*)((char*)lds + swz(pix, c)) = v;
    }
    __syncthreads();

    int wv = tid >> 6, lane = tid & 63;
    int lc = lane & 15, kg = lane >> 4;
    int p_local = wv * 16 + lc;
    bool valid = p_local < 63;
    int pl = valid ? p_local : 62;
    int pyl = pl / 21, pxl = pl % 21;
    int pixc[4];
    #pragma unroll
    for (int sub = 0; sub < 4; sub++)
        pixc[sub] = (2 * pyl + (sub >> 1) + 1) * 44 + (2 * pxl + (sub & 1) + 1);

    f32x4 bini[4];
    #pragma unroll
    for (int mt = 0; mt < 4; mt++) {
        float4 bq = *reinterpret_cast<const float4*>(bias + (mt << 4) + (kg << 2));
        bini[mt] = (f32x4){bq.x, bq.y, bq.z, bq.w};
    }

    const bf16x8* wvv = (const bf16x8*)wp;
    f32x4 acc[4][4];
    #pragma unroll
    for (int i = 0; i < 4; i++)
        #pragma unroll
        for (int j = 0; j < 4; j++)
            acc[i][j] = bini[i];

    for (int s = 0; s < 9; s++) {
        int offs = (s / 3 - 1) * 44 + (s % 3 - 1);
        #pragma unroll
        for (int t = 0; t < 2; t++) {
            int fbase = ((s * 2 + t) * 4) << 6;
            bf16x8 a0 = wvv[fbase + lane];
            bf16x8 a1 = wvv[fbase + 64 + lane];
            bf16x8 a2 = wvv[fbase + 128 + lane];
            bf16x8 a3 = wvv[fbase + 192 + lane];
            int c = (t << 2) + kg;
            bf16x8 b[4];
            #pragma unroll
            for (int sub = 0; sub < 4; sub++) {
                int pix = pixc[sub] + offs;
                b[sub] = *(const bf16x8*)((const char*)lds + swz(pix, c));
            }
            #pragma unroll
            for (int sub = 0; sub < 4; sub++) {
                acc[0][sub] = __builtin_amdgcn_mfma_f32_16x16x32_bf16(a0, b[sub], acc[0][sub], 0, 0, 0);
                acc[1][sub] = __builtin_amdgcn_mfma_f32_16x16x32_bf16(a1, b[sub], acc[1][sub], 0, 0, 0);
                acc[2][sub] = __builtin_amdgcn_mfma_f32_16x16x32_bf16(a2, b[sub], acc[2][sub], 0, 0, 0);
                acc[3][sub] = __builtin_amdgcn_mfma_f32_16x16x32_bf16(a3, b[sub], acc[3][sub], 0, 0, 0);
            }
        }
    }

    if (!valid) return;
    int p = tg * 63 + p_local;
    #pragma unroll
    for (int mt = 0; mt < 4; mt++) {
        unsigned short uo[4];
        #pragma unroll
        for (int r = 0; r < 4; r++) {
            float m = fmaxf(fmaxf(acc[mt][0][r], acc[mt][1][r]),
                            fmaxf(acc[mt][2][r], acc[mt][3][r]));
            uo[r] = f2bf(fmaxf(m, 0.f));
        }
        uint2 pk;
        pk.x = (unsigned)uo[0] | ((unsigned)uo[1] << 16);
        pk.y = (unsigned)uo[2] | ((unsigned)uo[3] << 16);
        *reinterpret_cast<uint2*>(out + ((size_t)img * HW3 + p) * DCH + (mt << 4) + (kg << 2)) = pk;
    }
}

// ---------------- conv3+conv4 fused (+q_norm for query imgs), 256 threads ----------------
__global__ __launch_bounds__(256) void conv34_fused(
    const unsigned short* __restrict__ act,   // [img][441][64] (conv2 out)
    const unsigned short* __restrict__ wp3, const unsigned short* __restrict__ wp4,
    const float* __restrict__ b3, const float* __restrict__ b4,
    unsigned short* __restrict__ a4out,       // support: [img][441][64]
    unsigned short* __restrict__ qlout)       // query:   [img][441][64] normalized
{
    int img = blockIdx.x;
    int tid = threadIdx.x;
    __shared__ unsigned short lds[529 * DCH];   // 67,712 B

    const unsigned short* ab = act + (size_t)img * HW3 * DCH;
    #pragma unroll
    for (int it = 0; it < 17; it++) {
        int idx = it * 256 + tid;
        if (idx < 529 * 8) {
            int pix = idx >> 3, c = idx & 7;
            int r = pix / 23, xx = pix % 23;
            int y = r - 1, x = xx - 1;
            bf16x8 v = (bf16x8)(short)0;
            if ((unsigned)y < (unsigned)H3 && (unsigned)x < (unsigned)H3)
                v = *(const bf16x8*)(ab + ((size_t)(y * H3 + x)) * DCH + (c << 3));
            *(bf16x8*)((char*)lds + swz(pix, c)) = v;
        }
    }
    __syncthreads();

    int wv = tid >> 6, lane = tid & 63;
    int lc = lane & 15, kg = lane >> 4;
    int pixBase[7];
    bool pv[7];
    #pragma unroll
    for (int i = 0; i < 7; i++) {
        int p = (wv * 7 + i) * 16 + lc;
        pv[i] = p < HW3;
        int pc = pv[i] ? p : HW3 - 1;
        pixBase[i] = (pc / 21) * 23 + (pc % 21);
    }

    // ---- conv3 ----
    f32x4 bini[4];
    #pragma unroll
    for (int mt = 0; mt < 4; mt++) {
        float4 bq = *reinterpret_cast<const float4*>(b3 + (mt << 4) + (kg << 2));
        bini[mt] = (f32x4){bq.x, bq.y, bq.z, bq.w};
    }

    f32x4 acc[7][4];
    #pragma unroll
    for (int i = 0; i < 7; i++)
        #pragma unroll
        for (int m = 0; m < 4; m++)
            acc[i][m] = bini[m];

    const bf16x8* wv3 = (const bf16x8*)wp3;
    for (int s = 0; s < 9; s++) {
        int offs = (s / 3) * 23 + (s % 3);
        #pragma unroll
        for (int t = 0; t < 2; t++) {
            int fbase = ((s * 2 + t) * 4) << 6;
            bf16x8 a0 = wv3[fbase + lane];
            bf16x8 a1 = wv3[fbase + 64 + lane];
            bf16x8 a2 = wv3[fbase + 128 + lane];
            bf16x8 a3 = wv3[fbase + 192 + lane];
            int c = (t << 2) + kg;
            #pragma unroll
            for (int i = 0; i < 7; i++) {
                int pix = pixBase[i] + offs;
                bf16x8 bb = *(const bf16x8*)((const char*)lds + swz(pix, c));
                acc[i][0] = __builtin_amdgcn_mfma_f32_16x16x32_bf16(a0, bb, acc[i][0], 0, 0, 0);
                acc[i][1] = __builtin_amdgcn_mfma_f32_16x16x32_bf16(a1, bb, acc[i][1], 0, 0, 0);
                acc[i][2] = __builtin_amdgcn_mfma_f32_16x16x32_bf16(a2, bb, acc[i][2], 0, 0, 0);
                acc[i][3] = __builtin_amdgcn_mfma_f32_16x16x32_bf16(a3, bb, acc[i][3], 0, 0, 0);
            }
        }
    }

    __syncthreads();   // all conv3 LDS reads done before overwrite

    #pragma unroll
    for (int i = 0; i < 7; i++) {
        if (!pv[i]) continue;
        int pix = pixBase[i] + 24;   // interior: (py+1)*23 + (px+1)
        #pragma unroll
        for (int mt = 0; mt < 4; mt++) {
            unsigned short uo[4];
            #pragma unroll
            for (int r = 0; r < 4; r++)
                uo[r] = f2bf(fmaxf(acc[i][mt][r], 0.f));
            uint2 pk;
            pk.x = (unsigned)uo[0] | ((unsigned)uo[1] << 16);
            pk.y = (unsigned)uo[2] | ((unsigned)uo[3] << 16);
            int c = (mt << 1) + (kg >> 1);
            *(uint2*)((char*)lds + swz(pix, c) + ((kg & 1) << 3)) = pk;
        }
    }
    // zero the 88 halo lines (704 16B chunks)
    #pragma unroll
    for (int it = 0; it < 3; it++) {
        int idx = it * 256 + tid;
        if (idx < 704) {
            int j = idx >> 3, c = idx & 7;
            int pix;
            if (j < 23)      pix = j;
            else if (j < 46) pix = 506 + (j - 23);
            else { int k = j - 46; pix = (1 + (k >> 1)) * 23 + (k & 1) * 22; }
            *(bf16x8*)((char*)lds + swz(pix, c)) = (bf16x8)(short)0;
        }
    }
    __syncthreads();

    // ---- conv4 ----
    #pragma unroll
    for (int mt = 0; mt < 4; mt++) {
        float4 bq = *reinterpret_cast<const float4*>(b4 + (mt << 4) + (kg << 2));
        bini[mt] = (f32x4){bq.x, bq.y, bq.z, bq.w};
    }
    #pragma unroll
    for (int i = 0; i < 7; i++)
        #pragma unroll
        for (int m = 0; m < 4; m++)
            acc[i][m] = bini[m];

    const bf16x8* wv4 = (const bf16x8*)wp4;
    for (int s = 0; s < 9; s++) {
        int offs = (s / 3) * 23 + (s % 3);
        #pragma unroll
        for (int t = 0; t < 2; t++) {
            int fbase = ((s * 2 + t) * 4) << 6;
            bf16x8 a0 = wv4[fbase + lane];
            bf16x8 a1 = wv4[fbase + 64 + lane];
            bf16x8 a2 = wv4[fbase + 128 + lane];
            bf16x8 a3 = wv4[fbase + 192 + lane];
            int c = (t << 2) + kg;
            #pragma unroll
            for (int i = 0; i < 7; i++) {
                int pix = pixBase[i] + offs;
                bf16x8 bb = *(const bf16x8*)((const char*)lds + swz(pix, c));
                acc[i][0] = __builtin_amdgcn_mfma_f32_16x16x32_bf16(a0, bb, acc[i][0], 0, 0, 0);
                acc[i][1] = __builtin_amdgcn_mfma_f32_16x16x32_bf16(a1, bb, acc[i][1], 0, 0, 0);
                acc[i][2] = __builtin_amdgcn_mfma_f32_16x16x32_bf16(a2, bb, acc[i][2], 0, 0, 0);
                acc[i][3] = __builtin_amdgcn_mfma_f32_16x16x32_bf16(a3, bb, acc[i][3], 0, 0, 0);
            }
        }
    }

    // ---- epilogue ----
    if (img < NQIMG) {
        #pragma unroll
        for (int i = 0; i < 7; i++) {
            float v[4][4];
            float ssq = 0.f;
            #pragma unroll
            for (int mt = 0; mt < 4; mt++)
                #pragma unroll
                for (int r = 0; r < 4; r++) {
                    float x = fmaxf(acc[i][mt][r], 0.f);
                    v[mt][r] = x;
                    ssq = fmaf(x, x, ssq);
                }
            ssq += __shfl_xor(ssq, 16, 64);
            ssq += __shfl_xor(ssq, 32, 64);
            float inv = 1.f / fmaxf(sqrtf(ssq), EPS);
            if (!pv[i]) continue;
            int p = (wv * 7 + i) * 16 + lc;
            #pragma unroll
            for (int mt = 0; mt < 4; mt++) {
                unsigned short uo[4];
                #pragma unroll
                for (int r = 0; r < 4; r++)
                    uo[r] = f2bf(v[mt][r] * inv);
                uint2 pk;
                pk.x = (unsigned)uo[0] | ((unsigned)uo[1] << 16);
                pk.y = (unsigned)uo[2] | ((unsigned)uo[3] << 16);
                *reinterpret_cast<uint2*>(qlout + ((size_t)img * HW3 + p) * DCH + (mt << 4) + (kg << 2)) = pk;
            }
        }
    } else {
        #pragma unroll
        for (int mt = 0; mt < 4; mt++) {
            #pragma unroll
            for (int i = 0; i < 7; i++) {
                if (!pv[i]) continue;
                int p = (wv * 7 + i) * 16 + lc;
                unsigned short uo[4];
                #pragma unroll
                for (int r = 0; r < 4; r++)
                    uo[r] = f2bf(fmaxf(acc[i][mt][r], 0.f));
                uint2 pk;
                pk.x = (unsigned)uo[0] | ((unsigned)uo[1] << 16);
                pk.y = (unsigned)uo[2] | ((unsigned)uo[3] << 16);
                *reinterpret_cast<uint2*>(a4out + ((size_t)img * HW3 + p) * DCH + (mt << 4) + (kg << 2)) = pk;
            }
        }
    }
}

// ---------------- support: mean over shots + L2-norm -> [bc][448][64] bf16, zero tail ----------------
__global__ __launch_bounds__(256) void s_mean_norm(
    const unsigned short* __restrict__ feat, unsigned short* __restrict__ s_local)
{
    int idx = blockIdx.x * 256 + threadIdx.x;
    if (idx >= BDIM * WAY * SST) return;
    int hw = idx % SST;
    int bc = idx / SST;
    bf16x8* o = (bf16x8*)(s_local + (size_t)idx * DCH);
    if (hw >= HW3) {
        #pragma unroll
        for (int g = 0; g < 8; g++) o[g] = (bf16x8)(short)0;
        return;
    }
    int img0 = NQIMG + bc * SHOT;
    float v[DCH];
    #pragma unroll
    for (int d = 0; d < DCH; d++) v[d] = 0.f;
    for (int sh = 0; sh < SHOT; sh++) {
        const bf16x8* f = (const bf16x8*)(feat + ((size_t)(img0 + sh) * HW3 + hw) * DCH);
        #pragma unroll
        for (int g = 0; g < 8; g++) {
            bf16x8 x = f[g];
            #pragma unroll
            for (int j = 0; j < 8; j++)
                v[g * 8 + j] += bf2f((unsigned short)x[j]);
        }
    }
    float ss = 0.f;
    #pragma unroll
    for (int d = 0; d < DCH; d++) {
        v[d] *= (1.f / SHOT);
        ss = fmaf(v[d], v[d], ss);
    }
    float inv = 1.f / fmaxf(sqrtf(ss), EPS);
    #pragma unroll
    for (int g = 0; g < 8; g++) {
        bf16x8 pk;
        #pragma unroll
        for (int j = 0; j < 8; j++) pk[j] = (short)f2bf(v[g * 8 + j] * inv);
        o[g] = pk;
    }
}

// ---------------- similarity via MFMA: s staged in swizzled LDS, 4 n-tiles/group ----------------
__global__ __launch_bounds__(256) void sim_mfma(
    const unsigned short* __restrict__ qloc,  // [150][441][64] bf16
    const unsigned short* __restrict__ sloc,  // [10][448][64] bf16 (tail zeroed)
    float* __restrict__ out)
{
    int blk = blockIdx.x;
    int imgq = blk / WAY, way = blk % WAY;
    int b = imgq / NQ;
    const unsigned short* qp = qloc + (size_t)imgq * HW3 * DCH;
    const unsigned short* sp = sloc + (size_t)(b * WAY + way) * SST * DCH;

    __shared__ unsigned short slds[SST * DCH];   // 57,344 B
    int tid = threadIdx.x;
    // stage s: coalesced 16B loads, swizzled LDS writes (both-sides swz)
    #pragma unroll
    for (int it = 0; it < 14; it++) {
        int idx = it * 256 + tid;              // 0..3583
        int pix = idx >> 3, c = idx & 7;
        bf16x8 v = *(const bf16x8*)(sp + ((size_t)pix << 6) + (c << 3));
        *(bf16x8*)((char*)slds + swz(pix, c)) = v;
    }
    __syncthreads();

    int wv = tid >> 6, lane = tid & 63;
    int lc = lane & 15, kg = lane >> 4;
    int mt0 = wv * 7;

    bf16x8 qa0[7], qa1[7];
    #pragma unroll
    for (int i = 0; i < 7; i++) {
        const unsigned short* qrow = qp + (size_t)((mt0 + i) * 16 + lc) * DCH + (kg << 3);
        qa0[i] = *(const bf16x8*)(qrow);
        qa1[i] = *(const bf16x8*)(qrow + 32);
    }
    f32x4 rmax[7];
    #pragma unroll
    for (int i = 0; i < 7; i++)
        rmax[i] = (f32x4){-1e30f, -1e30f, -1e30f, -1e30f};

    const f32x4 z4 = (f32x4){0.f, 0.f, 0.f, 0.f};

    // 6 groups of 4 full tiles (0..23) — LDS reads, conflict-free swz pattern
    #pragma unroll
    for (int g = 0; g < 6; g++) {
        bf16x8 s0[4], s1[4];
        #pragma unroll
        for (int u = 0; u < 4; u++) {
            int pix = (4 * g + u) * 16 + lc;
            s0[u] = *(const bf16x8*)((const char*)slds + swz(pix, kg));
            s1[u] = *(const bf16x8*)((const char*)slds + swz(pix, 4 + kg));
        }
        #pragma unroll
        for (int i = 0; i < 7; i++) {
            f32x4 a[4];
            #pragma unroll
            for (int u = 0; u < 4; u++) {
                a[u] = __builtin_amdgcn_mfma_f32_16x16x32_bf16(qa0[i], s0[u], z4, 0, 0, 0);
                a[u] = __builtin_amdgcn_mfma_f32_16x16x32_bf16(qa1[i], s1[u], a[u], 0, 0, 0);
            }
            #pragma unroll
            for (int r = 0; r < 4; r++) {
                float t = fmaxf(fmaxf(rmax[i][r], a[0][r]), a[1][r]);
                rmax[i][r] = fmaxf(fmaxf(t, a[2][r]), a[3][r]);
            }
        }
    }
    {   // tail tiles 24..27 (tile 27 cols 432..447: mask >= 441)
        bf16x8 s0[4], s1[4];
        #pragma unroll
        for (int u = 0; u < 4; u++) {
            int pix = (24 + u) * 16 + lc;
            s0[u] = *(const bf16x8*)((const char*)slds + swz(pix, kg));
            s1[u] = *(const bf16x8*)((const char*)slds + swz(pix, 4 + kg));
        }
        bool nval = (432 + lc) < HW3;
        #pragma unroll
        for (int i = 0; i < 7; i++) {
            f32x4 a[4];
            #pragma unroll
            for (int u = 0; u < 4; u++) {
                a[u] = __builtin_amdgcn_mfma_f32_16x16x32_bf16(qa0[i], s0[u], z4, 0, 0, 0);
                a[u] = __builtin_amdgcn_mfma_f32_16x16x32_bf16(qa1[i], s1[u], a[u], 0, 0, 0);
            }
            #pragma unroll
            for (int r = 0; r < 4; r++) {
                float t = fmaxf(fmaxf(rmax[i][r], a[0][r]), a[1][r]);
                rmax[i][r] = fmaxf(fmaxf(t, a[2][r]), nval ? a[3][r] : -1e30f);
            }
        }
    }

    float msum = 0.f;
    #pragma unroll
    for (int i = 0; i < 7; i++) {
        #pragma unroll
        for (int r = 0; r < 4; r++) {
            float v = rmax[i][r];
            v = fmaxf(v, __shfl_xor(v, 1, 64));
            v = fmaxf(v, __shfl_xor(v, 2, 64));
            v = fmaxf(v, __shfl_xor(v, 4, 64));
            v = fmaxf(v, __shfl_xor(v, 8, 64));
            int m = (mt0 + i) * 16 + (kg << 2) + r;
            if (lc == 0 && m < HW3) msum += v;
        }
    }
    #pragma unroll
    for (int off = 32; off > 0; off >>= 1)
        msum += __shfl_xor(msum, off, 64);
    __shared__ float red[4];
    if (lane == 0) red[wv] = msum;
    __syncthreads();
    if (tid == 0)
        out[(size_t)imgq * WAY + way] = (red[0] + red[1] + red[2] + red[3]) * (1.f / HW3);
}

extern "C" void kernel_launch(void* const* d_in, const int* in_sizes, int n_in,
                              void* d_out, int out_size, void* d_ws, size_t ws_size,
                              hipStream_t stream) {
    const float* query   = (const float*)d_in[0];
    const float* support = (const float*)d_in[1];
    const float* w1 = (const float*)d_in[2];
    const float* w2 = (const float*)d_in[3];
    const float* w3 = (const float*)d_in[4];
    const float* w4 = (const float*)d_in[5];
    const float* s1 = (const float*)d_in[6];
    const float* b1 = (const float*)d_in[7];
    const float* s2 = (const float*)d_in[8];
    const float* b2 = (const float*)d_in[9];
    const float* s3 = (const float*)d_in[10];
    const float* b3 = (const float*)d_in[11];
    const float* s4 = (const float*)d_in[12];
    const float* b4 = (const float*)d_in[13];
    float* out = (float*)d_out;

    char* ws = (char*)d_ws;
    unsigned short* A1  = (unsigned short*)(ws);              // 200*1764*64 bf16 = 45,158,400 B
    unsigned short* A2  = (unsigned short*)(ws + 45158400);   // 200*441*64 bf16 = 11,289,600 B
    unsigned short* A4  = (unsigned short*)(ws + 56448000);   // support feat (only >=150 written)
    unsigned short* QL  = (unsigned short*)(ws + 67737600);   // 150*441*64 bf16 = 8,467,200 B
    unsigned short* SL  = (unsigned short*)(ws + 76204800);   // 10*448*64 bf16 = 573,440 B
    unsigned short* WP2 = (unsigned short*)(ws + 76778240);   // 36864 bf16 = 73,728 B
    unsigned short* WP3 = (unsigned short*)(ws + 76851968);
    unsigned short* WP4 = (unsigned short*)(ws + 76925696);
    unsigned short* WP1 = (unsigned short*)(ws + 76999424);   // 2048 bf16 = 4,096 B
    unsigned short* PAD = (unsigned short*)(ws + 77003520);   // 200*3*7396 bf16 = 8,875,200 B

    prep<<<PAD_BLKS + W1_BLKS + W_BLKS, 256, 0, stream>>>(
        query, support, w1, s1, w2, s2, w3, s3, w4, s4, PAD, WP1, WP2, WP3, WP4);

    conv1_mfma<<<NIMG * 7, 256, 0, stream>>>(PAD, WP1, b1, A1);
    conv2_mfma_pool<<<NIMG * 7, 256, 0, stream>>>(A1, WP2, b2, A2);
    conv34_fused<<<NIMG, 256, 0, stream>>>(A2, WP3, WP4, b3, b4, A4, QL);

    s_mean_norm<<<(BDIM * WAY * SST + 255) / 256, 256, 0, stream>>>(A4, SL);

    sim_mfma<<<NQIMG * WAY, 256, 0, stream>>>(QL, SL, out);
}